// Round 8
// baseline (128.834 us; speedup 1.0000x reference)
//
#include <hip/hip_runtime.h>
#include <math.h>

#define NBINS 64
#define BATCH_N 884736    // 96*96*96
#define NTOT   1769472    // 2*BATCH_N
#define NCHUNK 13824      // BATCH_N / 64
#define ROWB  80          // tile row stride bytes (64 voxels + 16 pad, 16B aligned)
#define TILE_B 5440       // 68*80 bytes per tile (rows -1..66 padded)
#define WAVE_B 10880      // A+B tiles per wave
#define MROW 66           // merge region row stride (floats)
#define QS 190.0f         // weight quantization scale (max w=2/3 -> 127)
#define GBLK 896          // k_gemm blocks per batch (2 waves each)
#define GWAVES 1792       // waves per batch
#define KBLK 512          // k_minmax blocks
#define RBLKS 224         // k_redfin blocks = 4*2*28

// ws layout (bytes):
//   ghist  at   256 : float[2][4096]          (zeroed by k_gemm)
//   cnt    at 33024 : unsigned                 (zeroed by k_gemm)
//   kblk   at 36864 : uint4[512]               (plain-stored by k_minmax)
//   part   at 65536 : float[2][896][4096]      (fully stored by k_gemm)
#define OFF_GHIST 256
#define OFF_CNT  33024
#define OFF_KBLK 36864
#define OFF_PART 65536

typedef int  v4i __attribute__((ext_vector_type(4)));

// monotone float->uint key: max over keys == max over floats
__device__ __forceinline__ unsigned fkey(float x){
    unsigned u = __float_as_uint(x);
    return (u & 0x80000000u) ? ~u : (u | 0x80000000u);
}
__device__ __forceinline__ float fdecode(unsigned k){
    return __uint_as_float((k & 0x80000000u) ? (k ^ 0x80000000u) : ~k);
}

// cubic B-spline weights for the 4 bins it0-1..it0+2, u = frac(vt) in [0,1)
__device__ __forceinline__ void bw4(float u, float w[4]){
    float um = 1.f - u;
    float u2 = u*u, um2 = um*um;
    w[0] = um2*um*(1.f/6.f);
    w[3] = u2*u*(1.f/6.f);
    w[1] = 0.6666666666666667f - u2 + 0.5f*u2*u;
    w[2] = 0.6666666666666667f - um2 + 0.5f*um2*um;
}

// per-block min/max -> plain store into kblk[block] (no atomics, no memset needed)
__global__ void __launch_bounds__(256)
k_minmax(const float4* __restrict__ t4, const float4* __restrict__ s4,
         int n4, uint4* __restrict__ kblk){
    __shared__ unsigned red[4][4];   // [wave][key]

    unsigned mt=0u, mnt=0u, ms=0u, mns=0u;
    int stride = gridDim.x * blockDim.x;
    for (int i = blockIdx.x*blockDim.x + threadIdx.x; i < n4; i += stride){
        float4 a = t4[i];
        float4 b = s4[i];
        mt  = max(mt,  max(max(fkey(a.x),  fkey(a.y)),  max(fkey(a.z),  fkey(a.w))));
        mnt = max(mnt, max(max(fkey(-a.x), fkey(-a.y)), max(fkey(-a.z), fkey(-a.w))));
        ms  = max(ms,  max(max(fkey(b.x),  fkey(b.y)),  max(fkey(b.z),  fkey(b.w))));
        mns = max(mns, max(max(fkey(-b.x), fkey(-b.y)), max(fkey(-b.z), fkey(-b.w))));
    }
    #pragma unroll
    for (int off = 32; off; off >>= 1){
        mt  = max(mt,  __shfl_down(mt,  off));
        mnt = max(mnt, __shfl_down(mnt, off));
        ms  = max(ms,  __shfl_down(ms,  off));
        mns = max(mns, __shfl_down(mns, off));
    }
    int wid = threadIdx.x >> 6;
    if ((threadIdx.x & 63) == 0){
        red[wid][0] = mt; red[wid][1] = mnt; red[wid][2] = ms; red[wid][3] = mns;
    }
    __syncthreads();
    if (threadIdx.x == 0){
        uint4 q;
        q.x = max(max(red[0][0], red[1][0]), max(red[2][0], red[3][0]));
        q.y = max(max(red[0][1], red[1][1]), max(red[2][1], red[3][1]));
        q.z = max(max(red[0][2], red[1][2]), max(red[2][2], red[3][2]));
        q.w = max(max(red[0][3], red[1][3]), max(red[2][3], red[3][3]));
        kblk[blockIdx.x] = q;
    }
}

// joint histogram as tall-skinny GEMM on int8 (wave-private LDS tiles, i8 MFMA).
// Prologue: reduce kblk -> global min/max; zero ghist+cnt for the next kernel.
// Epilogue: 2-wave LDS merge, one plain-stored partial per block.
__global__ void __launch_bounds__(128)
k_gemm(const float* __restrict__ t, const float* __restrict__ s,
       const uint4* __restrict__ kblk, float* __restrict__ ghist,
       unsigned* __restrict__ cnt, float* __restrict__ part){
    __shared__ int4 smem4[1360];           // 21760 B = 2 waves * (A+B i8 tiles)
    __shared__ unsigned kred[2][4];

    int lane = threadIdx.x & 63;
    int warp = threadIdx.x >> 6;
    int rrow = lane & 15;                  // fragment row/col within 16-tile
    int kgrp = lane >> 4;                  // k-group (16 bytes each for K=64 i8)
    int b = blockIdx.y;

    // zero ghist + counter for k_redfin (kernel-boundary visibility)
    if (b == 0 && blockIdx.x < 8){
        #pragma unroll
        for (int k = 0; k < 8; ++k)
            ghist[blockIdx.x*1024 + k*128 + threadIdx.x] = 0.f;
        if (blockIdx.x == 0 && threadIdx.x == 0) *cnt = 0u;
    }

    // reduce the 512 per-block key quads (redundant per block; ~L2-hit)
    {
        unsigned m0=0u, m1=0u, m2=0u, m3=0u;
        for (int i = threadIdx.x; i < KBLK; i += 128){
            uint4 q = kblk[i];
            m0 = max(m0, q.x); m1 = max(m1, q.y);
            m2 = max(m2, q.z); m3 = max(m3, q.w);
        }
        #pragma unroll
        for (int off = 32; off; off >>= 1){
            m0 = max(m0, __shfl_down(m0, off));
            m1 = max(m1, __shfl_down(m1, off));
            m2 = max(m2, __shfl_down(m2, off));
            m3 = max(m3, __shfl_down(m3, off));
        }
        if (lane == 0){
            kred[warp][0] = m0; kred[warp][1] = m1;
            kred[warp][2] = m2; kred[warp][3] = m3;
        }
        __syncthreads();
    }
    float tmax =  fdecode(max(kred[0][0], kred[1][0]));
    float tmin = -fdecode(max(kred[0][1], kred[1][1]));
    float smax =  fdecode(max(kred[0][2], kred[1][2]));
    float smin = -fdecode(max(kred[0][3], kred[1][3]));
    float tsc = 64.f / (tmax - tmin);
    float ssc = 64.f / (smax - smin);

    char* As = (char*)smem4 + warp*WAVE_B; // this wave's tiles
    char* Bs = As + TILE_B;

    // initial clear of this wave's tiles (wave-private: no barrier needed)
    {
        int4* wz = (int4*)As;
        int4 z4 = {0,0,0,0};
        #pragma unroll
        for (int i = 0; i < 11; ++i){
            int idx = i*64 + lane;
            if (idx < WAVE_B/16) wz[idx] = z4;
        }
    }

    const float* tb = t + (size_t)b*BATCH_N;
    const float* sb = s + (size_t)b*BATCH_N;

    v4i acc[4][4];
    #pragma unroll
    for (int i = 0; i < 4; ++i)
        #pragma unroll
        for (int j = 0; j < 4; ++j)
            acc[i][j] = (v4i){0,0,0,0};

    int c0 = blockIdx.x*2 + warp;          // wave index within batch
    float tcur = tb[(size_t)c0*64 + lane];
    float scur = sb[(size_t)c0*64 + lane];

    for (int c = c0; c < NCHUNK; c += GWAVES){
        // prefetch next chunk
        int cn = c + GWAVES; if (cn >= NCHUNK) cn = c;
        float tnext = tb[(size_t)cn*64 + lane];
        float snext = sb[(size_t)cn*64 + lane];

        float vt = (tcur - tmin) * tsc;    // in [0,64]
        float vs = (scur - smin) * ssc;
        int it0 = (int)floorf(vt);         // 0..64
        int is0 = (int)floorf(vs);
        float wt[4], wsv[4];
        bw4(vt - (float)it0, wt);
        bw4(vs - (float)is0, wsv);

        // quantized scatter: lane owns voxel column `lane`; padded rows it0..it0+3
        // (bin it0-1..it0+2 shifted +1), unconditional — pad rows are never read.
        char* pa = As + it0*ROWB + lane;
        char* pb = Bs + is0*ROWB + lane;
        #pragma unroll
        for (int k = 0; k < 4; ++k){
            pa[k*ROWB] = (char)__float2int_rn(wt[k]  * QS);
            pb[k*ROWB] = (char)__float2int_rn(wsv[k] * QS);
        }

        // fragments + MFMA (same-wave DS ops complete in order)
        v4i af[4], bf[4];
        #pragma unroll
        for (int m = 0; m < 4; ++m)
            af[m] = *(const v4i*)(As + (m*16 + rrow + 1)*ROWB + kgrp*16);
        #pragma unroll
        for (int n = 0; n < 4; ++n)
            bf[n] = *(const v4i*)(Bs + (n*16 + rrow + 1)*ROWB + kgrp*16);
        #pragma unroll
        for (int m = 0; m < 4; ++m)
            #pragma unroll
            for (int n = 0; n < 4; ++n)
                acc[m][n] = __builtin_amdgcn_mfma_i32_16x16x64_i8(af[m], bf[n], acc[m][n], 0, 0, 0);

        // zero-restore the scattered entries
        __asm__ volatile("" ::: "memory");
        #pragma unroll
        for (int k = 0; k < 4; ++k){
            pa[k*ROWB] = 0;
            pb[k*ROWB] = 0;
        }

        tcur = tnext; scur = snext;
    }

    // merge: reuse tile LDS (dead now) as f32 staging; wave0 stores, wave1 adds.
    const float dq = 1.f / (QS*QS);
    float* fm = (float*)smem4;             // 64*66*4 = 16896 B <= 21760 B
    __syncthreads();
    if (warp == 0){
        #pragma unroll
        for (int m = 0; m < 4; ++m)
            #pragma unroll
            for (int n = 0; n < 4; ++n)
                #pragma unroll
                for (int r = 0; r < 4; ++r)
                    fm[(m*16 + kgrp*4 + r)*MROW + n*16 + rrow] = (float)acc[m][n][r] * dq;
    }
    __syncthreads();
    if (warp == 1){
        #pragma unroll
        for (int m = 0; m < 4; ++m)
            #pragma unroll
            for (int n = 0; n < 4; ++n)
                #pragma unroll
                for (int r = 0; r < 4; ++r)
                    fm[(m*16 + kgrp*4 + r)*MROW + n*16 + rrow] += (float)acc[m][n][r] * dq;
    }
    __syncthreads();
    // plain coalesced store of this block's partial (16 KB)
    float* gp = part + ((size_t)(b*GBLK + blockIdx.x))*4096;
    for (int i = threadIdx.x; i < 4096; i += 128)
        gp[i] = fm[(i >> 6)*MROW + (i & 63)];
}

__device__ __forceinline__ float blockReduceSum(float v, float* red){
    #pragma unroll
    for (int off = 32; off; off >>= 1) v += __shfl_down(v, off);
    int wid = threadIdx.x >> 6, lane = threadIdx.x & 63;
    __syncthreads();              // protect red[] from previous round
    if (lane == 0) red[wid] = v;
    __syncthreads();
    return red[0] + red[1] + red[2] + red[3];
}

// reduce 896 partials/batch -> ghist (few atomics), then the LAST block to
// finish computes the NMI scalar (ticket counter + fences; agent-scope
// atomic loads of ghist dodge any stale per-XCD cache line).
__global__ void __launch_bounds__(256)
k_redfin(const float* __restrict__ part, float* __restrict__ ghist,
         unsigned* __restrict__ cnt, float* __restrict__ out){
    __shared__ float sh[2*4096];
    __shared__ float red[4];
    __shared__ int lastflag;

    int b = blockIdx.y;
    int bin4 = (blockIdx.x*256 + threadIdx.x)*4;   // 0..4092
    int p0 = blockIdx.z*32;                        // 28 groups * 32 partials = 896
    const float* base = part + (size_t)(b*GBLK + p0)*4096 + bin4;
    float4 acc4 = {0.f,0.f,0.f,0.f};
    #pragma unroll
    for (int g = 0; g < 2; ++g){
        float4 v[16];
        #pragma unroll
        for (int i = 0; i < 16; ++i)
            v[i] = *(const float4*)(base + (size_t)(g*16 + i)*4096);
        float4 s;
        s.x = ((v[0].x+v[1].x)+(v[2].x+v[3].x)) + ((v[4].x+v[5].x)+(v[6].x+v[7].x))
            + ((v[8].x+v[9].x)+(v[10].x+v[11].x)) + ((v[12].x+v[13].x)+(v[14].x+v[15].x));
        s.y = ((v[0].y+v[1].y)+(v[2].y+v[3].y)) + ((v[4].y+v[5].y)+(v[6].y+v[7].y))
            + ((v[8].y+v[9].y)+(v[10].y+v[11].y)) + ((v[12].y+v[13].y)+(v[14].y+v[15].y));
        s.z = ((v[0].z+v[1].z)+(v[2].z+v[3].z)) + ((v[4].z+v[5].z)+(v[6].z+v[7].z))
            + ((v[8].z+v[9].z)+(v[10].z+v[11].z)) + ((v[12].z+v[13].z)+(v[14].z+v[15].z));
        s.w = ((v[0].w+v[1].w)+(v[2].w+v[3].w)) + ((v[4].w+v[5].w)+(v[6].w+v[7].w))
            + ((v[8].w+v[9].w)+(v[10].w+v[11].w)) + ((v[12].w+v[13].w)+(v[14].w+v[15].w));
        acc4.x += s.x; acc4.y += s.y; acc4.z += s.z; acc4.w += s.w;
    }
    float* g = ghist + b*4096 + bin4;
    unsafeAtomicAdd(&g[0], acc4.x);
    unsafeAtomicAdd(&g[1], acc4.y);
    unsafeAtomicAdd(&g[2], acc4.z);
    unsafeAtomicAdd(&g[3], acc4.w);

    // ticket: last block to finish does the final reduction
    __threadfence();
    if (threadIdx.x == 0)
        lastflag = (atomicAdd(cnt, 1u) == RBLKS - 1) ? 1 : 0;
    __syncthreads();
    if (!lastflag) return;
    __threadfence();

    int tid = threadIdx.x;
    for (int i = tid; i < 8192; i += 256)
        sh[i] = __hip_atomic_load(&ghist[i], __ATOMIC_RELAXED, __HIP_MEMORY_SCOPE_AGENT);
    __syncthreads();

    float loc = 0.f;
    for (int i = tid; i < 8192; i += 256) loc += sh[i];
    float total = blockReduceSum(loc, red);
    float inv = 1.f / total;

    float nmi[2];
    for (int bb = 0; bb < 2; ++bb){
        const float* h = sh + bb*4096;
        float lj = 0.f;
        for (int i = tid; i < 4096; i += 256){
            float p = h[i]*inv;
            lj += p*logf(p + 1e-12f);
        }
        float Hj = -blockReduceSum(lj, red);
        float lt = 0.f;
        if (tid < 64){
            float r = 0.f;
            for (int j = 0; j < 64; ++j) r += h[tid*64 + j];
            float p = r*inv;
            lt = p*logf(p + 1e-12f);
        }
        float Ht = -blockReduceSum(lt, red);
        float ls = 0.f;
        if (tid < 64){
            float c = 0.f;
            for (int j = 0; j < 64; ++j) c += h[j*64 + tid];
            float p = c*inv;
            ls = p*logf(p + 1e-12f);
        }
        float Hs = -blockReduceSum(ls, red);
        nmi[bb] = (Ht + Hs) / Hj;
    }
    if (tid == 0) out[0] = -0.5f*(nmi[0] + nmi[1]);
}

extern "C" void kernel_launch(void* const* d_in, const int* in_sizes, int n_in,
                              void* d_out, int out_size, void* d_ws, size_t ws_size,
                              hipStream_t stream) {
    const float* t = (const float*)d_in[0];
    const float* s = (const float*)d_in[1];
    float* out = (float*)d_out;
    float*    ghist = (float*)((char*)d_ws + OFF_GHIST);
    unsigned* cnt   = (unsigned*)((char*)d_ws + OFF_CNT);
    uint4*    kblk  = (uint4*)((char*)d_ws + OFF_KBLK);
    float*    part  = (float*)((char*)d_ws + OFF_PART);

    // no memset: kblk plain-stored by k_minmax; ghist+cnt zeroed inside k_gemm;
    // part fully overwritten by k_gemm.
    k_minmax<<<KBLK, 256, 0, stream>>>((const float4*)t, (const float4*)s, NTOT/4, kblk);
    k_gemm<<<dim3(GBLK, 2), 128, 0, stream>>>(t, s, kblk, ghist, cnt, part);
    k_redfin<<<dim3(4, 2, 28), 256, 0, stream>>>(part, ghist, cnt, out);
}

// Round 9
// 104.512 us; speedup vs baseline: 1.2327x; 1.2327x over previous
//
#include <hip/hip_runtime.h>
#include <math.h>

#define NBINS 64
#define BATCH_N 884736    // 96*96*96
#define NTOT   1769472    // 2*BATCH_N
#define NCHUNK 13824      // BATCH_N / 64
#define ROWB  80          // tile row stride bytes (64 voxels + 16 pad, 16B aligned)
#define TILE_B 5440       // 68*80 bytes per tile (rows -1..66 padded)
#define WAVE_B 10880      // A+B tiles per wave
#define MROW 66           // merge region row stride (floats)
#define QS 190.0f         // weight quantization scale (max w=2/3 -> 127)
#define GBLK 896          // k_gemm blocks per batch (2 waves each)
#define GWAVES 1792       // waves per batch
#define KBLK 512          // k_minmax blocks

// ws layout (bytes):
//   ghist  at   256 : float[2][4096]          (zeroed by k_gemm prologue)
//   kblk   at 36864 : uint4[512]               (plain-stored by k_minmax)
//   part   at 65536 : float[2][896][4096]      (fully stored by k_gemm)
#define OFF_GHIST 256
#define OFF_KBLK 36864
#define OFF_PART 65536

typedef int  v4i __attribute__((ext_vector_type(4)));

// monotone float->uint key: max over keys == max over floats
__device__ __forceinline__ unsigned fkey(float x){
    unsigned u = __float_as_uint(x);
    return (u & 0x80000000u) ? ~u : (u | 0x80000000u);
}
__device__ __forceinline__ float fdecode(unsigned k){
    return __uint_as_float((k & 0x80000000u) ? (k ^ 0x80000000u) : ~k);
}

// cubic B-spline weights for the 4 bins it0-1..it0+2, u = frac(vt) in [0,1)
__device__ __forceinline__ void bw4(float u, float w[4]){
    float um = 1.f - u;
    float u2 = u*u, um2 = um*um;
    w[0] = um2*um*(1.f/6.f);
    w[3] = u2*u*(1.f/6.f);
    w[1] = 0.6666666666666667f - u2 + 0.5f*u2*u;
    w[2] = 0.6666666666666667f - um2 + 0.5f*um2*um;
}

// per-block min/max -> plain store into kblk[block] (no atomics, no memset needed)
__global__ void __launch_bounds__(256)
k_minmax(const float4* __restrict__ t4, const float4* __restrict__ s4,
         int n4, uint4* __restrict__ kblk){
    __shared__ unsigned red[4][4];   // [wave][key]

    unsigned mt=0u, mnt=0u, ms=0u, mns=0u;
    int stride = gridDim.x * blockDim.x;
    for (int i = blockIdx.x*blockDim.x + threadIdx.x; i < n4; i += stride){
        float4 a = t4[i];
        float4 b = s4[i];
        mt  = max(mt,  max(max(fkey(a.x),  fkey(a.y)),  max(fkey(a.z),  fkey(a.w))));
        mnt = max(mnt, max(max(fkey(-a.x), fkey(-a.y)), max(fkey(-a.z), fkey(-a.w))));
        ms  = max(ms,  max(max(fkey(b.x),  fkey(b.y)),  max(fkey(b.z),  fkey(b.w))));
        mns = max(mns, max(max(fkey(-b.x), fkey(-b.y)), max(fkey(-b.z), fkey(-b.w))));
    }
    #pragma unroll
    for (int off = 32; off; off >>= 1){
        mt  = max(mt,  __shfl_down(mt,  off));
        mnt = max(mnt, __shfl_down(mnt, off));
        ms  = max(ms,  __shfl_down(ms,  off));
        mns = max(mns, __shfl_down(mns, off));
    }
    int wid = threadIdx.x >> 6;
    if ((threadIdx.x & 63) == 0){
        red[wid][0] = mt; red[wid][1] = mnt; red[wid][2] = ms; red[wid][3] = mns;
    }
    __syncthreads();
    if (threadIdx.x == 0){
        uint4 q;
        q.x = max(max(red[0][0], red[1][0]), max(red[2][0], red[3][0]));
        q.y = max(max(red[0][1], red[1][1]), max(red[2][1], red[3][1]));
        q.z = max(max(red[0][2], red[1][2]), max(red[2][2], red[3][2]));
        q.w = max(max(red[0][3], red[1][3]), max(red[2][3], red[3][3]));
        kblk[blockIdx.x] = q;
    }
}

// joint histogram as tall-skinny GEMM on int8 (wave-private LDS tiles, i8 MFMA).
// Prologue: reduce kblk -> global min/max; zero ghist for k_reduce (kernel boundary).
// Epilogue: 2-wave LDS merge, one plain-stored partial per block.
__global__ void __launch_bounds__(128)
k_gemm(const float* __restrict__ t, const float* __restrict__ s,
       const uint4* __restrict__ kblk, float* __restrict__ ghist,
       float* __restrict__ part){
    __shared__ int4 smem4[1360];           // 21760 B = 2 waves * (A+B i8 tiles)
    __shared__ unsigned kred[2][4];

    int lane = threadIdx.x & 63;
    int warp = threadIdx.x >> 6;
    int rrow = lane & 15;                  // fragment row/col within 16-tile
    int kgrp = lane >> 4;                  // k-group (16 bytes each for K=64 i8)
    int b = blockIdx.y;

    // zero ghist for k_reduce (visible at kernel boundary)
    if (b == 0 && blockIdx.x < 8){
        #pragma unroll
        for (int k = 0; k < 8; ++k)
            ghist[blockIdx.x*1024 + k*128 + threadIdx.x] = 0.f;
    }

    // reduce the 512 per-block key quads (redundant per block; ~L2-hit)
    {
        unsigned m0=0u, m1=0u, m2=0u, m3=0u;
        for (int i = threadIdx.x; i < KBLK; i += 128){
            uint4 q = kblk[i];
            m0 = max(m0, q.x); m1 = max(m1, q.y);
            m2 = max(m2, q.z); m3 = max(m3, q.w);
        }
        #pragma unroll
        for (int off = 32; off; off >>= 1){
            m0 = max(m0, __shfl_down(m0, off));
            m1 = max(m1, __shfl_down(m1, off));
            m2 = max(m2, __shfl_down(m2, off));
            m3 = max(m3, __shfl_down(m3, off));
        }
        if (lane == 0){
            kred[warp][0] = m0; kred[warp][1] = m1;
            kred[warp][2] = m2; kred[warp][3] = m3;
        }
        __syncthreads();
    }
    float tmax =  fdecode(max(kred[0][0], kred[1][0]));
    float tmin = -fdecode(max(kred[0][1], kred[1][1]));
    float smax =  fdecode(max(kred[0][2], kred[1][2]));
    float smin = -fdecode(max(kred[0][3], kred[1][3]));
    float tsc = 64.f / (tmax - tmin);
    float ssc = 64.f / (smax - smin);

    char* As = (char*)smem4 + warp*WAVE_B; // this wave's tiles
    char* Bs = As + TILE_B;

    // initial clear of this wave's tiles (wave-private: no barrier needed)
    {
        int4* wz = (int4*)As;
        int4 z4 = {0,0,0,0};
        #pragma unroll
        for (int i = 0; i < 11; ++i){
            int idx = i*64 + lane;
            if (idx < WAVE_B/16) wz[idx] = z4;
        }
    }

    const float* tb = t + (size_t)b*BATCH_N;
    const float* sb = s + (size_t)b*BATCH_N;

    v4i acc[4][4];
    #pragma unroll
    for (int i = 0; i < 4; ++i)
        #pragma unroll
        for (int j = 0; j < 4; ++j)
            acc[i][j] = (v4i){0,0,0,0};

    int c0 = blockIdx.x*2 + warp;          // wave index within batch
    float tcur = tb[(size_t)c0*64 + lane];
    float scur = sb[(size_t)c0*64 + lane];

    for (int c = c0; c < NCHUNK; c += GWAVES){
        // prefetch next chunk
        int cn = c + GWAVES; if (cn >= NCHUNK) cn = c;
        float tnext = tb[(size_t)cn*64 + lane];
        float snext = sb[(size_t)cn*64 + lane];

        float vt = (tcur - tmin) * tsc;    // in [0,64]
        float vs = (scur - smin) * ssc;
        int it0 = (int)floorf(vt);         // 0..64
        int is0 = (int)floorf(vs);
        float wt[4], wsv[4];
        bw4(vt - (float)it0, wt);
        bw4(vs - (float)is0, wsv);

        // quantized scatter: lane owns voxel column `lane`; padded rows it0..it0+3
        // (bin it0-1..it0+2 shifted +1), unconditional — pad rows are never read.
        char* pa = As + it0*ROWB + lane;
        char* pb = Bs + is0*ROWB + lane;
        #pragma unroll
        for (int k = 0; k < 4; ++k){
            pa[k*ROWB] = (char)__float2int_rn(wt[k]  * QS);
            pb[k*ROWB] = (char)__float2int_rn(wsv[k] * QS);
        }

        // fragments + MFMA (same-wave DS ops complete in order)
        v4i af[4], bf[4];
        #pragma unroll
        for (int m = 0; m < 4; ++m)
            af[m] = *(const v4i*)(As + (m*16 + rrow + 1)*ROWB + kgrp*16);
        #pragma unroll
        for (int n = 0; n < 4; ++n)
            bf[n] = *(const v4i*)(Bs + (n*16 + rrow + 1)*ROWB + kgrp*16);
        #pragma unroll
        for (int m = 0; m < 4; ++m)
            #pragma unroll
            for (int n = 0; n < 4; ++n)
                acc[m][n] = __builtin_amdgcn_mfma_i32_16x16x64_i8(af[m], bf[n], acc[m][n], 0, 0, 0);

        // zero-restore the scattered entries
        __asm__ volatile("" ::: "memory");
        #pragma unroll
        for (int k = 0; k < 4; ++k){
            pa[k*ROWB] = 0;
            pb[k*ROWB] = 0;
        }

        tcur = tnext; scur = snext;
    }

    // merge: reuse tile LDS (dead now) as f32 staging; wave0 stores, wave1 adds.
    const float dq = 1.f / (QS*QS);
    float* fm = (float*)smem4;             // 64*66*4 = 16896 B <= 21760 B
    __syncthreads();
    if (warp == 0){
        #pragma unroll
        for (int m = 0; m < 4; ++m)
            #pragma unroll
            for (int n = 0; n < 4; ++n)
                #pragma unroll
                for (int r = 0; r < 4; ++r)
                    fm[(m*16 + kgrp*4 + r)*MROW + n*16 + rrow] = (float)acc[m][n][r] * dq;
    }
    __syncthreads();
    if (warp == 1){
        #pragma unroll
        for (int m = 0; m < 4; ++m)
            #pragma unroll
            for (int n = 0; n < 4; ++n)
                #pragma unroll
                for (int r = 0; r < 4; ++r)
                    fm[(m*16 + kgrp*4 + r)*MROW + n*16 + rrow] += (float)acc[m][n][r] * dq;
    }
    __syncthreads();
    // plain coalesced store of this block's partial (16 KB)
    float* gp = part + ((size_t)(b*GBLK + blockIdx.x))*4096;
    for (int i = threadIdx.x; i < 4096; i += 128)
        gp[i] = fm[(i >> 6)*MROW + (i & 63)];
}

// reduce 896 partials/batch -> ghist. grid (4, 2, 28): each thread sums 32
// partials for 4 consecutive bins (float4), loads deeply in flight, then 4
// atomic adds (229K atomics = 0.9 MB write-through — negligible).
__global__ void __launch_bounds__(256)
k_reduce(const float* __restrict__ part, float* __restrict__ ghist){
    int b = blockIdx.y;
    int bin4 = (blockIdx.x*256 + threadIdx.x)*4;   // 0..4092
    int p0 = blockIdx.z*32;                        // 28 groups * 32 partials = 896
    const float* base = part + (size_t)(b*GBLK + p0)*4096 + bin4;
    float4 acc4 = {0.f,0.f,0.f,0.f};
    #pragma unroll
    for (int g = 0; g < 2; ++g){
        float4 v[16];
        #pragma unroll
        for (int i = 0; i < 16; ++i)
            v[i] = *(const float4*)(base + (size_t)(g*16 + i)*4096);
        float4 s;
        s.x = ((v[0].x+v[1].x)+(v[2].x+v[3].x)) + ((v[4].x+v[5].x)+(v[6].x+v[7].x))
            + ((v[8].x+v[9].x)+(v[10].x+v[11].x)) + ((v[12].x+v[13].x)+(v[14].x+v[15].x));
        s.y = ((v[0].y+v[1].y)+(v[2].y+v[3].y)) + ((v[4].y+v[5].y)+(v[6].y+v[7].y))
            + ((v[8].y+v[9].y)+(v[10].y+v[11].y)) + ((v[12].y+v[13].y)+(v[14].y+v[15].y));
        s.z = ((v[0].z+v[1].z)+(v[2].z+v[3].z)) + ((v[4].z+v[5].z)+(v[6].z+v[7].z))
            + ((v[8].z+v[9].z)+(v[10].z+v[11].z)) + ((v[12].z+v[13].z)+(v[14].z+v[15].z));
        s.w = ((v[0].w+v[1].w)+(v[2].w+v[3].w)) + ((v[4].w+v[5].w)+(v[6].w+v[7].w))
            + ((v[8].w+v[9].w)+(v[10].w+v[11].w)) + ((v[12].w+v[13].w)+(v[14].w+v[15].w));
        acc4.x += s.x; acc4.y += s.y; acc4.z += s.z; acc4.w += s.w;
    }
    float* g = ghist + b*4096 + bin4;
    unsafeAtomicAdd(&g[0], acc4.x);
    unsafeAtomicAdd(&g[1], acc4.y);
    unsafeAtomicAdd(&g[2], acc4.z);
    unsafeAtomicAdd(&g[3], acc4.w);
}

__device__ __forceinline__ float blockReduceSum(float v, float* red){
    #pragma unroll
    for (int off = 32; off; off >>= 1) v += __shfl_down(v, off);
    int wid = threadIdx.x >> 6, lane = threadIdx.x & 63;
    __syncthreads();              // protect red[] from previous round
    if (lane == 0) red[wid] = v;
    __syncthreads();
    return red[0] + red[1] + red[2] + red[3];
}

__global__ void k_final(const float* __restrict__ hist, float* __restrict__ out){
    __shared__ float sh[2*4096];
    __shared__ float red[4];
    int tid = threadIdx.x;
    for (int i = tid; i < 8192; i += 256) sh[i] = hist[i];
    __syncthreads();

    float loc = 0.f;
    for (int i = tid; i < 8192; i += 256) loc += sh[i];
    float total = blockReduceSum(loc, red);
    float inv = 1.f / total;

    float nmi[2];
    for (int b = 0; b < 2; ++b){
        const float* h = sh + b*4096;
        float lj = 0.f;
        for (int i = tid; i < 4096; i += 256){
            float p = h[i]*inv;
            lj += p*logf(p + 1e-12f);
        }
        float Hj = -blockReduceSum(lj, red);
        float lt = 0.f;
        if (tid < 64){
            float r = 0.f;
            for (int j = 0; j < 64; ++j) r += h[tid*64 + j];
            float p = r*inv;
            lt = p*logf(p + 1e-12f);
        }
        float Ht = -blockReduceSum(lt, red);
        float ls = 0.f;
        if (tid < 64){
            float c = 0.f;
            for (int j = 0; j < 64; ++j) c += h[j*64 + tid];
            float p = c*inv;
            ls = p*logf(p + 1e-12f);
        }
        float Hs = -blockReduceSum(ls, red);
        nmi[b] = (Ht + Hs) / Hj;
    }
    if (tid == 0) out[0] = -0.5f*(nmi[0] + nmi[1]);
}

extern "C" void kernel_launch(void* const* d_in, const int* in_sizes, int n_in,
                              void* d_out, int out_size, void* d_ws, size_t ws_size,
                              hipStream_t stream) {
    const float* t = (const float*)d_in[0];
    const float* s = (const float*)d_in[1];
    float* out = (float*)d_out;
    float* ghist = (float*)((char*)d_ws + OFF_GHIST);
    uint4* kblk  = (uint4*)((char*)d_ws + OFF_KBLK);
    float* part  = (float*)((char*)d_ws + OFF_PART);

    // no memset node: kblk plain-stored by k_minmax; ghist zeroed in k_gemm;
    // part fully overwritten by k_gemm. Kernel boundaries provide visibility.
    k_minmax<<<KBLK, 256, 0, stream>>>((const float4*)t, (const float4*)s, NTOT/4, kblk);
    k_gemm<<<dim3(GBLK, 2), 128, 0, stream>>>(t, s, kblk, ghist, part);
    k_reduce<<<dim3(4, 2, 28), 256, 0, stream>>>(part, ghist);
    k_final<<<1, 256, 0, stream>>>(ghist, out);
}

// Round 10
// 104.155 us; speedup vs baseline: 1.2369x; 1.0034x over previous
//
#include <hip/hip_runtime.h>
#include <math.h>

#define NBINS 64
#define BATCH_N 884736    // 96*96*96
#define NTOT   1769472    // 2*BATCH_N
#define NCHUNK 13824      // BATCH_N / 64
#define ROWB  80          // tile row stride bytes (64 voxels + 16 pad, 16B aligned)
#define TILE_B 5440       // 68*80 bytes per tile (rows -1..66 padded)
#define WAVE_B 10880      // A+B tiles per wave
#define MROW 66           // merge region row stride (floats)
#define QS 190.0f         // weight quantization scale (max w=2/3 -> 127)
#define GBLK 864          // k_gemm blocks per batch (2 waves each)
#define GWAVES 1728       // waves per batch: 13824/1728 = exactly 8 chunks/wave
#define KBLK 512          // k_minmax blocks

// ws layout (bytes):
//   ghist  at   256 : float[2][4096]          (zeroed by k_gemm prologue)
//   kblk   at 36864 : uint4[512]               (plain-stored by k_minmax)
//   part   at 65536 : float[2][864][4096]      (fully stored by k_gemm)
#define OFF_GHIST 256
#define OFF_KBLK 36864
#define OFF_PART 65536

typedef int  v4i __attribute__((ext_vector_type(4)));

// monotone float->uint key: max over keys == max over floats
__device__ __forceinline__ unsigned fkey(float x){
    unsigned u = __float_as_uint(x);
    return (u & 0x80000000u) ? ~u : (u | 0x80000000u);
}
__device__ __forceinline__ float fdecode(unsigned k){
    return __uint_as_float((k & 0x80000000u) ? (k ^ 0x80000000u) : ~k);
}

// cubic B-spline weights for the 4 bins it0-1..it0+2, u = frac(vt) in [0,1)
__device__ __forceinline__ void bw4(float u, float w[4]){
    float um = 1.f - u;
    float u2 = u*u, um2 = um*um;
    w[0] = um2*um*(1.f/6.f);
    w[3] = u2*u*(1.f/6.f);
    w[1] = 0.6666666666666667f - u2 + 0.5f*u2*u;
    w[2] = 0.6666666666666667f - um2 + 0.5f*um2*um;
}

// per-block min/max -> plain store into kblk[block] (no atomics, no memset needed)
__global__ void __launch_bounds__(256)
k_minmax(const float4* __restrict__ t4, const float4* __restrict__ s4,
         int n4, uint4* __restrict__ kblk){
    __shared__ unsigned red[4][4];   // [wave][key]

    unsigned mt=0u, mnt=0u, ms=0u, mns=0u;
    int stride = gridDim.x * blockDim.x;
    for (int i = blockIdx.x*blockDim.x + threadIdx.x; i < n4; i += stride){
        float4 a = t4[i];
        float4 b = s4[i];
        mt  = max(mt,  max(max(fkey(a.x),  fkey(a.y)),  max(fkey(a.z),  fkey(a.w))));
        mnt = max(mnt, max(max(fkey(-a.x), fkey(-a.y)), max(fkey(-a.z), fkey(-a.w))));
        ms  = max(ms,  max(max(fkey(b.x),  fkey(b.y)),  max(fkey(b.z),  fkey(b.w))));
        mns = max(mns, max(max(fkey(-b.x), fkey(-b.y)), max(fkey(-b.z), fkey(-b.w))));
    }
    #pragma unroll
    for (int off = 32; off; off >>= 1){
        mt  = max(mt,  __shfl_down(mt,  off));
        mnt = max(mnt, __shfl_down(mnt, off));
        ms  = max(ms,  __shfl_down(ms,  off));
        mns = max(mns, __shfl_down(mns, off));
    }
    int wid = threadIdx.x >> 6;
    if ((threadIdx.x & 63) == 0){
        red[wid][0] = mt; red[wid][1] = mnt; red[wid][2] = ms; red[wid][3] = mns;
    }
    __syncthreads();
    if (threadIdx.x == 0){
        uint4 q;
        q.x = max(max(red[0][0], red[1][0]), max(red[2][0], red[3][0]));
        q.y = max(max(red[0][1], red[1][1]), max(red[2][1], red[3][1]));
        q.z = max(max(red[0][2], red[1][2]), max(red[2][2], red[3][2]));
        q.w = max(max(red[0][3], red[1][3]), max(red[2][3], red[3][3]));
        kblk[blockIdx.x] = q;
    }
}

// joint histogram as tall-skinny GEMM on int8 (wave-private LDS tiles, i8 MFMA).
// Exactly 8 chunks per wave (balanced); depth-2 global prefetch; unroll-2 body.
__global__ void __launch_bounds__(128)
k_gemm(const float* __restrict__ t, const float* __restrict__ s,
       const uint4* __restrict__ kblk, float* __restrict__ ghist,
       float* __restrict__ part){
    __shared__ int4 smem4[1360];           // 21760 B = 2 waves * (A+B i8 tiles)
    __shared__ unsigned kred[2][4];

    int lane = threadIdx.x & 63;
    int warp = threadIdx.x >> 6;
    int rrow = lane & 15;                  // fragment row/col within 16-tile
    int kgrp = lane >> 4;                  // k-group (16 bytes each for K=64 i8)
    int b = blockIdx.y;

    // zero ghist for k_reduce (visible at kernel boundary)
    if (b == 0 && blockIdx.x < 8){
        #pragma unroll
        for (int k = 0; k < 8; ++k)
            ghist[blockIdx.x*1024 + k*128 + threadIdx.x] = 0.f;
    }

    // reduce the 512 per-block key quads (redundant per block; ~L2-hit)
    {
        unsigned m0=0u, m1=0u, m2=0u, m3=0u;
        for (int i = threadIdx.x; i < KBLK; i += 128){
            uint4 q = kblk[i];
            m0 = max(m0, q.x); m1 = max(m1, q.y);
            m2 = max(m2, q.z); m3 = max(m3, q.w);
        }
        #pragma unroll
        for (int off = 32; off; off >>= 1){
            m0 = max(m0, __shfl_down(m0, off));
            m1 = max(m1, __shfl_down(m1, off));
            m2 = max(m2, __shfl_down(m2, off));
            m3 = max(m3, __shfl_down(m3, off));
        }
        if (lane == 0){
            kred[warp][0] = m0; kred[warp][1] = m1;
            kred[warp][2] = m2; kred[warp][3] = m3;
        }
        __syncthreads();
    }
    float tmax =  fdecode(max(kred[0][0], kred[1][0]));
    float tmin = -fdecode(max(kred[0][1], kred[1][1]));
    float smax =  fdecode(max(kred[0][2], kred[1][2]));
    float smin = -fdecode(max(kred[0][3], kred[1][3]));
    float tsc = 64.f / (tmax - tmin);
    float ssc = 64.f / (smax - smin);

    char* As = (char*)smem4 + warp*WAVE_B; // this wave's tiles
    char* Bs = As + TILE_B;

    // initial clear of this wave's tiles (wave-private: no barrier needed)
    {
        int4* wz = (int4*)As;
        int4 z4 = {0,0,0,0};
        #pragma unroll
        for (int i = 0; i < 11; ++i){
            int idx = i*64 + lane;
            if (idx < WAVE_B/16) wz[idx] = z4;
        }
    }

    const float* tb = t + (size_t)b*BATCH_N;
    const float* sb = s + (size_t)b*BATCH_N;

    v4i acc[4][4];
    #pragma unroll
    for (int i = 0; i < 4; ++i)
        #pragma unroll
        for (int j = 0; j < 4; ++j)
            acc[i][j] = (v4i){0,0,0,0};

    int c0 = blockIdx.x*2 + warp;          // wave index within batch
    // depth-2 prefetch pipeline
    float tq0 = tb[(size_t)c0*64 + lane];
    float sq0 = sb[(size_t)c0*64 + lane];
    float tq1 = tb[(size_t)(c0 + GWAVES)*64 + lane];
    float sq1 = sb[(size_t)(c0 + GWAVES)*64 + lane];

    #pragma unroll 2
    for (int it = 0; it < 8; ++it){
        // issue prefetch for chunk it+2 (clamped to a safe in-range address)
        int cpre = c0 + (it < 6 ? (it + 2)*GWAVES : 0);
        float tnn = tb[(size_t)cpre*64 + lane];
        float snn = sb[(size_t)cpre*64 + lane];

        float vt = (tq0 - tmin) * tsc;     // in [0,64]
        float vs = (sq0 - smin) * ssc;
        int it0 = (int)floorf(vt);         // 0..64
        int is0 = (int)floorf(vs);
        float wt[4], wsv[4];
        bw4(vt - (float)it0, wt);
        bw4(vs - (float)is0, wsv);

        // quantized scatter: lane owns voxel column `lane`; padded rows it0..it0+3
        // (bin it0-1..it0+2 shifted +1), unconditional — pad rows are never read.
        char* pa = As + it0*ROWB + lane;
        char* pb = Bs + is0*ROWB + lane;
        #pragma unroll
        for (int k = 0; k < 4; ++k){
            pa[k*ROWB] = (char)__float2int_rn(wt[k]  * QS);
            pb[k*ROWB] = (char)__float2int_rn(wsv[k] * QS);
        }

        // fragments + MFMA (same-wave DS ops complete in order)
        v4i af[4], bf[4];
        #pragma unroll
        for (int m = 0; m < 4; ++m)
            af[m] = *(const v4i*)(As + (m*16 + rrow + 1)*ROWB + kgrp*16);
        #pragma unroll
        for (int n = 0; n < 4; ++n)
            bf[n] = *(const v4i*)(Bs + (n*16 + rrow + 1)*ROWB + kgrp*16);
        #pragma unroll
        for (int m = 0; m < 4; ++m)
            #pragma unroll
            for (int n = 0; n < 4; ++n)
                acc[m][n] = __builtin_amdgcn_mfma_i32_16x16x64_i8(af[m], bf[n], acc[m][n], 0, 0, 0);

        // zero-restore the scattered entries
        __asm__ volatile("" ::: "memory");
        #pragma unroll
        for (int k = 0; k < 4; ++k){
            pa[k*ROWB] = 0;
            pb[k*ROWB] = 0;
        }

        tq0 = tq1; sq0 = sq1;
        tq1 = tnn; sq1 = snn;
    }

    // merge: reuse tile LDS (dead now) as f32 staging; wave0 stores, wave1 adds.
    const float dq = 1.f / (QS*QS);
    float* fm = (float*)smem4;             // 64*66*4 = 16896 B <= 21760 B
    __syncthreads();
    if (warp == 0){
        #pragma unroll
        for (int m = 0; m < 4; ++m)
            #pragma unroll
            for (int n = 0; n < 4; ++n)
                #pragma unroll
                for (int r = 0; r < 4; ++r)
                    fm[(m*16 + kgrp*4 + r)*MROW + n*16 + rrow] = (float)acc[m][n][r] * dq;
    }
    __syncthreads();
    if (warp == 1){
        #pragma unroll
        for (int m = 0; m < 4; ++m)
            #pragma unroll
            for (int n = 0; n < 4; ++n)
                #pragma unroll
                for (int r = 0; r < 4; ++r)
                    fm[(m*16 + kgrp*4 + r)*MROW + n*16 + rrow] += (float)acc[m][n][r] * dq;
    }
    __syncthreads();
    // plain coalesced store of this block's partial (16 KB)
    float* gp = part + ((size_t)(b*GBLK + blockIdx.x))*4096;
    for (int i = threadIdx.x; i < 4096; i += 128)
        gp[i] = fm[(i >> 6)*MROW + (i & 63)];
}

// reduce 864 partials/batch -> ghist. grid (4, 2, 27): each thread sums 32
// partials for 4 consecutive bins (float4), loads deeply in flight, then 4
// atomic adds (221K atomics = 0.9 MB write-through — negligible).
__global__ void __launch_bounds__(256)
k_reduce(const float* __restrict__ part, float* __restrict__ ghist){
    int b = blockIdx.y;
    int bin4 = (blockIdx.x*256 + threadIdx.x)*4;   // 0..4092
    int p0 = blockIdx.z*32;                        // 27 groups * 32 partials = 864
    const float* base = part + (size_t)(b*GBLK + p0)*4096 + bin4;
    float4 acc4 = {0.f,0.f,0.f,0.f};
    #pragma unroll
    for (int g = 0; g < 2; ++g){
        float4 v[16];
        #pragma unroll
        for (int i = 0; i < 16; ++i)
            v[i] = *(const float4*)(base + (size_t)(g*16 + i)*4096);
        float4 s;
        s.x = ((v[0].x+v[1].x)+(v[2].x+v[3].x)) + ((v[4].x+v[5].x)+(v[6].x+v[7].x))
            + ((v[8].x+v[9].x)+(v[10].x+v[11].x)) + ((v[12].x+v[13].x)+(v[14].x+v[15].x));
        s.y = ((v[0].y+v[1].y)+(v[2].y+v[3].y)) + ((v[4].y+v[5].y)+(v[6].y+v[7].y))
            + ((v[8].y+v[9].y)+(v[10].y+v[11].y)) + ((v[12].y+v[13].y)+(v[14].y+v[15].y));
        s.z = ((v[0].z+v[1].z)+(v[2].z+v[3].z)) + ((v[4].z+v[5].z)+(v[6].z+v[7].z))
            + ((v[8].z+v[9].z)+(v[10].z+v[11].z)) + ((v[12].z+v[13].z)+(v[14].z+v[15].z));
        s.w = ((v[0].w+v[1].w)+(v[2].w+v[3].w)) + ((v[4].w+v[5].w)+(v[6].w+v[7].w))
            + ((v[8].w+v[9].w)+(v[10].w+v[11].w)) + ((v[12].w+v[13].w)+(v[14].w+v[15].w));
        acc4.x += s.x; acc4.y += s.y; acc4.z += s.z; acc4.w += s.w;
    }
    float* g = ghist + b*4096 + bin4;
    unsafeAtomicAdd(&g[0], acc4.x);
    unsafeAtomicAdd(&g[1], acc4.y);
    unsafeAtomicAdd(&g[2], acc4.z);
    unsafeAtomicAdd(&g[3], acc4.w);
}

__device__ __forceinline__ float blockReduceSum(float v, float* red){
    #pragma unroll
    for (int off = 32; off; off >>= 1) v += __shfl_down(v, off);
    int wid = threadIdx.x >> 6, lane = threadIdx.x & 63;
    __syncthreads();              // protect red[] from previous round
    if (lane == 0) red[wid] = v;
    __syncthreads();
    return red[0] + red[1] + red[2] + red[3];
}

__global__ void k_final(const float* __restrict__ hist, float* __restrict__ out){
    __shared__ float sh[2*4096];
    __shared__ float red[4];
    int tid = threadIdx.x;
    for (int i = tid; i < 8192; i += 256) sh[i] = hist[i];
    __syncthreads();

    float loc = 0.f;
    for (int i = tid; i < 8192; i += 256) loc += sh[i];
    float total = blockReduceSum(loc, red);
    float inv = 1.f / total;

    float nmi[2];
    for (int b = 0; b < 2; ++b){
        const float* h = sh + b*4096;
        float lj = 0.f;
        for (int i = tid; i < 4096; i += 256){
            float p = h[i]*inv;
            lj += p*logf(p + 1e-12f);
        }
        float Hj = -blockReduceSum(lj, red);
        float lt = 0.f;
        if (tid < 64){
            float r = 0.f;
            for (int j = 0; j < 64; ++j) r += h[tid*64 + j];
            float p = r*inv;
            lt = p*logf(p + 1e-12f);
        }
        float Ht = -blockReduceSum(lt, red);
        float ls = 0.f;
        if (tid < 64){
            float c = 0.f;
            for (int j = 0; j < 64; ++j) c += h[j*64 + tid];
            float p = c*inv;
            ls = p*logf(p + 1e-12f);
        }
        float Hs = -blockReduceSum(ls, red);
        nmi[b] = (Ht + Hs) / Hj;
    }
    if (tid == 0) out[0] = -0.5f*(nmi[0] + nmi[1]);
}

extern "C" void kernel_launch(void* const* d_in, const int* in_sizes, int n_in,
                              void* d_out, int out_size, void* d_ws, size_t ws_size,
                              hipStream_t stream) {
    const float* t = (const float*)d_in[0];
    const float* s = (const float*)d_in[1];
    float* out = (float*)d_out;
    float* ghist = (float*)((char*)d_ws + OFF_GHIST);
    uint4* kblk  = (uint4*)((char*)d_ws + OFF_KBLK);
    float* part  = (float*)((char*)d_ws + OFF_PART);

    // no memset node: kblk plain-stored by k_minmax; ghist zeroed in k_gemm;
    // part fully overwritten by k_gemm. Kernel boundaries provide visibility.
    k_minmax<<<KBLK, 256, 0, stream>>>((const float4*)t, (const float4*)s, NTOT/4, kblk);
    k_gemm<<<dim3(GBLK, 2), 128, 0, stream>>>(t, s, kblk, ghist, part);
    k_reduce<<<dim3(4, 2, 27), 256, 0, stream>>>(part, ghist);
    k_final<<<1, 256, 0, stream>>>(ghist, out);
}